// Round 7
// baseline (126.590 us; speedup 1.0000x reference)
//
#include <hip/hip_runtime.h>
#include <hip/hip_fp16.h>

#define K 8

// clang native vector types — required for __builtin_nontemporal_load/store
typedef float    vfloat4 __attribute__((ext_vector_type(4)));
typedef int      vint4   __attribute__((ext_vector_type(4)));
typedef unsigned vuint2  __attribute__((ext_vector_type(2)));

// ---------- precompute: full Phong per POINT -> half4 color (8B record) ----------
__global__ __launch_bounds__(256) void shade_points_kernel(
    const float* __restrict__ points,
    const float* __restrict__ normals,
    const float* __restrict__ light_location,
    const float* __restrict__ light_ambient,
    const float* __restrict__ light_diffuse,
    const float* __restrict__ light_specular,
    const float* __restrict__ mat_ambient,
    const float* __restrict__ mat_diffuse,
    const float* __restrict__ mat_specular,
    const float* __restrict__ camera_position,
    const int*   __restrict__ shininess_p,
    vuint2*      __restrict__ ctab,
    int P)
{
    const int i = blockIdx.x * blockDim.x + threadIdx.x;
    if (i >= P) return;

    const size_t b = (size_t)i * 3;
    const float px = points[b],  py = points[b + 1],  pz = points[b + 2];
    const float nx = normals[b], ny = normals[b + 1], nz = normals[b + 2];

    const float Lx = light_location[0], Ly = light_location[1], Lz = light_location[2];
    const float Cx = camera_position[0], Cy = camera_position[1], Cz = camera_position[2];
    const int   shin = shininess_p[0];

    // dir_light = normalize(light - p)
    float lx = Lx - px, ly = Ly - py, lz = Lz - pz;
    float ll = lx * lx + ly * ly + lz * lz;
    float li = (ll > 1e-12f) ? rsqrtf(ll) : 1e6f;
    lx *= li; ly *= li; lz *= li;

    const float cosv = nx * lx + ny * ly + nz * lz;

    // view = normalize(camera - p)
    float vx = Cx - px, vy = Cy - py, vz = Cz - pz;
    float vv = vx * vx + vy * vy + vz * vz;
    float vi = (vv > 1e-12f) ? rsqrtf(vv) : 1e6f;
    vx *= vi; vy *= vi; vz *= vi;

    // reflect = 2*cos*n - dir_light
    const float c2 = 2.0f * cosv;
    const float rx = c2 * nx - lx;
    const float ry = c2 * ny - ly;
    const float rz = c2 * nz - lz;

    float alpha = fmaxf(vx * rx + vy * ry + vz * rz, 0.0f);
    if (!(cosv > 0.0f)) alpha = 0.0f;

    // alpha ** shin (pow by squaring; shin uniform)
    float sp = 1.0f, bb = alpha;
    int e = shin;
    while (e > 0) {
        if (e & 1) sp *= bb;
        bb *= bb;
        e >>= 1;
    }

    const float rc = fmaxf(cosv, 0.0f);
    const float c0 = light_ambient[0] * mat_ambient[0]
                   + light_diffuse[0] * mat_diffuse[0] * rc
                   + light_specular[0] * mat_specular[0] * sp;
    const float c1 = light_ambient[1] * mat_ambient[1]
                   + light_diffuse[1] * mat_diffuse[1] * rc
                   + light_specular[1] * mat_specular[1] * sp;
    const float c2c = light_ambient[2] * mat_ambient[2]
                   + light_diffuse[2] * mat_diffuse[2] * rc
                   + light_specular[2] * mat_specular[2] * sp;

    const unsigned h0 = __half_as_ushort(__float2half(c0));
    const unsigned h1 = __half_as_ushort(__float2half(c1));
    const unsigned h2 = __half_as_ushort(__float2half(c2c));
    vuint2 r = {h0 | (h1 << 16), h2};
    ctab[i] = r;
}

// ---------- composite: gather 8 colors, L1-normalized weighted sum ----------
template <bool PACKED>
__global__ __launch_bounds__(256) void composite_kernel(
    const int*    __restrict__ idx,
    const float*  __restrict__ dists,
    const vuint2* __restrict__ ctab,
    const float*  __restrict__ points,
    const float*  __restrict__ normals,
    const float*  __restrict__ light_location,
    const float*  __restrict__ light_ambient,
    const float*  __restrict__ light_diffuse,
    const float*  __restrict__ light_specular,
    const float*  __restrict__ mat_ambient,
    const float*  __restrict__ mat_diffuse,
    const float*  __restrict__ mat_specular,
    const float*  __restrict__ camera_position,
    const int*    __restrict__ shininess_p,
    float*        __restrict__ out,
    int n_pix)
{
    const int p = blockIdx.x * blockDim.x + threadIdx.x;
    if (p >= n_pix) return;

    // streamed per-pixel inputs (nontemporal, coalesced 16B)
    const vint4*   idxv = reinterpret_cast<const vint4*>(idx   + (size_t)p * K);
    const vfloat4* dstv = reinterpret_cast<const vfloat4*>(dists + (size_t)p * K);
    vint4   i0 = __builtin_nontemporal_load(idxv);
    vint4   i1 = __builtin_nontemporal_load(idxv + 1);
    vfloat4 d0 = __builtin_nontemporal_load(dstv);
    vfloat4 d1 = __builtin_nontemporal_load(dstv + 1);

    int   ik[K] = {i0.x, i0.y, i0.z, i0.w, i1.x, i1.y, i1.z, i1.w};
    float dk[K] = {d0.x, d0.y, d0.z, d0.w, d1.x, d1.y, d1.z, d1.w};

    // gather phase: one 8B color per sample
    vuint2 cv[K];
#pragma unroll
    for (int k = 0; k < K; ++k) {
        const int ii = (ik[k] < 0) ? 0 : ik[k];
        if (PACKED) cv[k] = ctab[(size_t)ii];
    }

    // weights
    float w[K];
    float wsum = 0.f;
#pragma unroll
    for (int k = 0; k < K; ++k) {
        float d = dk[k];
        float m = (d != -1.0f) ? d : 0.0f;
        w[k] = m;
        wsum += fabsf(m);
    }
    const float winv = 1.0f / fmaxf(wsum, 1e-12f);

    float acc0 = 0.f, acc1 = 0.f, acc2 = 0.f;

    if (PACKED) {
#pragma unroll
        for (int k = 0; k < K; ++k) {
            const float c0 = __half2float(__ushort_as_half((unsigned short)(cv[k].x & 0xffffu)));
            const float c1 = __half2float(__ushort_as_half((unsigned short)(cv[k].x >> 16)));
            const float c2 = __half2float(__ushort_as_half((unsigned short)(cv[k].y & 0xffffu)));
            const float wk = w[k];
            acc0 += wk * c0;
            acc1 += wk * c1;
            acc2 += wk * c2;
        }
    } else {
        // fallback: full Phong inline (no workspace)
        const float Lx = light_location[0], Ly = light_location[1], Lz = light_location[2];
        const float Cx = camera_position[0], Cy = camera_position[1], Cz = camera_position[2];
        const float amb0 = light_ambient[0] * mat_ambient[0];
        const float amb1 = light_ambient[1] * mat_ambient[1];
        const float amb2 = light_ambient[2] * mat_ambient[2];
        const float dif0 = light_diffuse[0] * mat_diffuse[0];
        const float dif1 = light_diffuse[1] * mat_diffuse[1];
        const float dif2 = light_diffuse[2] * mat_diffuse[2];
        const float spc0 = light_specular[0] * mat_specular[0];
        const float spc1 = light_specular[1] * mat_specular[1];
        const float spc2 = light_specular[2] * mat_specular[2];
        const int   shin = shininess_p[0];
#pragma unroll
        for (int k = 0; k < K; ++k) {
            const int ii = (ik[k] < 0) ? 0 : ik[k];
            const size_t base = (size_t)ii * 3;
            const float px = points[base], py = points[base + 1], pz = points[base + 2];
            const float nx = normals[base], ny = normals[base + 1], nz = normals[base + 2];

            float lx = Lx - px, ly = Ly - py, lz = Lz - pz;
            float ll = lx * lx + ly * ly + lz * lz;
            float li = (ll > 1e-12f) ? rsqrtf(ll) : 1e6f;
            lx *= li; ly *= li; lz *= li;
            const float cosv = nx * lx + ny * ly + nz * lz;

            float vx = Cx - px, vy = Cy - py, vz = Cz - pz;
            float vv = vx * vx + vy * vy + vz * vz;
            float vi = (vv > 1e-12f) ? rsqrtf(vv) : 1e6f;
            vx *= vi; vy *= vi; vz *= vi;

            const float c2 = 2.0f * cosv;
            const float rx = c2 * nx - lx;
            const float ry = c2 * ny - ly;
            const float rz = c2 * nz - lz;

            float alpha = fmaxf(vx * rx + vy * ry + vz * rz, 0.0f);
            if (!(cosv > 0.0f)) alpha = 0.0f;

            float sp = 1.0f, bb = alpha;
            int e = shin;
            while (e > 0) { if (e & 1) sp *= bb; bb *= bb; e >>= 1; }

            const float rc = fmaxf(cosv, 0.0f);
            const float wk = w[k];
            acc0 += wk * (amb0 + dif0 * rc + spc0 * sp);
            acc1 += wk * (amb1 + dif1 * rc + spc1 * sp);
            acc2 += wk * (amb2 + dif2 * rc + spc2 * sp);
        }
    }

    float* o = out + (size_t)p * 3;
    __builtin_nontemporal_store(acc0 * winv, o);
    __builtin_nontemporal_store(acc1 * winv, o + 1);
    __builtin_nontemporal_store(acc2 * winv, o + 2);
}

extern "C" void kernel_launch(void* const* d_in, const int* in_sizes, int n_in,
                              void* d_out, int out_size, void* d_ws, size_t ws_size,
                              hipStream_t stream) {
    const int*   idx             = (const int*)d_in[0];
    const float* dists           = (const float*)d_in[1];
    const float* points          = (const float*)d_in[2];
    const float* normals         = (const float*)d_in[3];
    const float* light_location  = (const float*)d_in[4];
    const float* light_ambient   = (const float*)d_in[5];
    const float* light_diffuse   = (const float*)d_in[6];
    const float* light_specular  = (const float*)d_in[7];
    const float* mat_ambient     = (const float*)d_in[8];
    const float* mat_diffuse     = (const float*)d_in[9];
    const float* mat_specular    = (const float*)d_in[10];
    const float* camera_position = (const float*)d_in[11];
    const int*   shininess       = (const int*)d_in[12];
    float*       out             = (float*)d_out;

    const int n_pix = in_sizes[0] / K;       // N*H*W
    const int P     = in_sizes[2] / 3;       // number of points

    const int block = 256;
    const int grid  = (n_pix + block - 1) / block;

    const size_t need = (size_t)P * sizeof(vuint2);
    if (ws_size >= need) {
        vuint2* ctab = (vuint2*)d_ws;
        shade_points_kernel<<<(P + block - 1) / block, block, 0, stream>>>(
            points, normals, light_location, light_ambient, light_diffuse,
            light_specular, mat_ambient, mat_diffuse, mat_specular,
            camera_position, shininess, ctab, P);
        composite_kernel<true><<<grid, block, 0, stream>>>(
            idx, dists, ctab, points, normals, light_location, light_ambient,
            light_diffuse, light_specular, mat_ambient, mat_diffuse,
            mat_specular, camera_position, shininess, out, n_pix);
    } else {
        composite_kernel<false><<<grid, block, 0, stream>>>(
            idx, dists, nullptr, points, normals, light_location, light_ambient,
            light_diffuse, light_specular, mat_ambient, mat_diffuse,
            mat_specular, camera_position, shininess, out, n_pix);
    }
}